// Round 1
// baseline (544.008 us; speedup 1.0000x reference)
//
#include <hip/hip_runtime.h>

#define N_NODES 100000
#define N_EDGES 1600000
#define D_IN 256
#define D_OUT 128

// ---------------------------------------------------------------------------
// GEMM: support[N, 128] = X[N, 256] @ W[256, 128]   (fp32, vector ALU)
// BM=64, BN=128 (full N), BK=32; 256 threads; each thread computes 4x8.
// ---------------------------------------------------------------------------
__global__ __launch_bounds__(256) void gemm_kernel(const float* __restrict__ X,
                                                   const float* __restrict__ W,
                                                   float* __restrict__ support) {
    __shared__ float As[64][36];   // pad 32->36 (144B row stride, 16B aligned)
    __shared__ float Bs[32][128];

    const int tid = threadIdx.x;
    const int block_row = blockIdx.x * 64;
    const int tx = tid & 15;         // 16 col-groups of 8
    const int ty = tid >> 4;         // 16 row-groups of 4
    const int row0 = ty * 4;
    const int col0 = tx * 8;

    float acc[4][8];
    #pragma unroll
    for (int i = 0; i < 4; ++i)
        #pragma unroll
        for (int j = 0; j < 8; ++j)
            acc[i][j] = 0.0f;

    for (int kb = 0; kb < D_IN / 32; ++kb) {
        const int k0 = kb * 32;
        // --- load A tile: 64 x 32 floats = 512 float4
        #pragma unroll
        for (int it = tid; it < 512; it += 256) {
            int r  = it >> 3;
            int k4 = it & 7;
            int grow = block_row + r;
            float4 v = make_float4(0.f, 0.f, 0.f, 0.f);
            if (grow < N_NODES)
                v = *(const float4*)&X[(size_t)grow * D_IN + k0 + k4 * 4];
            *(float4*)&As[r][k4 * 4] = v;
        }
        // --- load B tile: 32 x 128 floats = 1024 float4
        #pragma unroll
        for (int it = tid; it < 1024; it += 256) {
            int k  = it >> 5;
            int n4 = it & 31;
            float4 v = *(const float4*)&W[(size_t)(k0 + k) * D_OUT + n4 * 4];
            *(float4*)&Bs[k][n4 * 4] = v;
        }
        __syncthreads();

        #pragma unroll 8
        for (int kk = 0; kk < 32; ++kk) {
            float a0 = As[row0 + 0][kk];
            float a1 = As[row0 + 1][kk];
            float a2 = As[row0 + 2][kk];
            float a3 = As[row0 + 3][kk];
            float4 b0 = *(const float4*)&Bs[kk][col0];
            float4 b1 = *(const float4*)&Bs[kk][col0 + 4];
            float bb[8] = {b0.x, b0.y, b0.z, b0.w, b1.x, b1.y, b1.z, b1.w};
            #pragma unroll
            for (int j = 0; j < 8; ++j) {
                acc[0][j] = fmaf(a0, bb[j], acc[0][j]);
                acc[1][j] = fmaf(a1, bb[j], acc[1][j]);
                acc[2][j] = fmaf(a2, bb[j], acc[2][j]);
                acc[3][j] = fmaf(a3, bb[j], acc[3][j]);
            }
        }
        __syncthreads();
    }

    #pragma unroll
    for (int i = 0; i < 4; ++i) {
        int grow = block_row + row0 + i;
        if (grow < N_NODES) {
            float4 c0 = make_float4(acc[i][0], acc[i][1], acc[i][2], acc[i][3]);
            float4 c1 = make_float4(acc[i][4], acc[i][5], acc[i][6], acc[i][7]);
            *(float4*)&support[(size_t)grow * D_OUT + col0]     = c0;
            *(float4*)&support[(size_t)grow * D_OUT + col0 + 4] = c1;
        }
    }
}

// ---------------------------------------------------------------------------
// CSR build: histogram -> exclusive scan (3 kernels) -> bin
// ---------------------------------------------------------------------------
__global__ __launch_bounds__(256) void hist_kernel(const int* __restrict__ rows,
                                                   int* __restrict__ counts) {
    int e = blockIdx.x * 256 + threadIdx.x;
    if (e < N_EDGES) atomicAdd(&counts[rows[e]], 1);
}

// chunk = 2048 per block (256 threads x 8)
#define SCAN_CHUNK 2048
#define SCAN_NBLK ((N_NODES + SCAN_CHUNK - 1) / SCAN_CHUNK)   // 49

__global__ __launch_bounds__(256) void scan1_kernel(const int* __restrict__ counts,
                                                    int* __restrict__ lexcl,
                                                    int* __restrict__ partials) {
    __shared__ int tsum[256];
    const int tid = threadIdx.x;
    const int base = blockIdx.x * SCAN_CHUNK + tid * 8;
    int vals[8];
    int s = 0;
    #pragma unroll
    for (int j = 0; j < 8; ++j) {
        int i = base + j;
        int v = (i < N_NODES) ? counts[i] : 0;
        vals[j] = s;          // thread-local exclusive
        s += v;
    }
    tsum[tid] = s;
    __syncthreads();
    // Hillis-Steele inclusive scan over 256 thread totals
    for (int off = 1; off < 256; off <<= 1) {
        int t = (tid >= off) ? tsum[tid - off] : 0;
        __syncthreads();
        tsum[tid] += t;
        __syncthreads();
    }
    int incl = tsum[tid];
    int texcl = incl - s;
    if (tid == 255) partials[blockIdx.x] = incl;
    #pragma unroll
    for (int j = 0; j < 8; ++j) {
        int i = base + j;
        if (i < N_NODES) lexcl[i] = texcl + vals[j];
    }
}

__global__ __launch_bounds__(64) void scan2_kernel(const int* __restrict__ partials,
                                                   int* __restrict__ partial_base) {
    int tid = threadIdx.x;
    int v = (tid < SCAN_NBLK) ? partials[tid] : 0;
    int x = v;
    #pragma unroll
    for (int off = 1; off < 64; off <<= 1) {
        int t = __shfl_up(x, off, 64);
        if (tid >= off) x += t;
    }
    if (tid < SCAN_NBLK) partial_base[tid] = x - v;   // exclusive
}

__global__ __launch_bounds__(256) void scan3_kernel(const int* __restrict__ lexcl,
                                                    const int* __restrict__ partial_base,
                                                    int* __restrict__ row_ptr,
                                                    int* __restrict__ cursor) {
    const int pb = partial_base[blockIdx.x];
    const int base = blockIdx.x * SCAN_CHUNK + threadIdx.x * 8;
    #pragma unroll
    for (int j = 0; j < 8; ++j) {
        int i = base + j;
        if (i < N_NODES) {
            int v = pb + lexcl[i];
            row_ptr[i] = v;
            cursor[i]  = v;
        }
    }
    if (blockIdx.x == 0 && threadIdx.x == 0) row_ptr[N_NODES] = N_EDGES;
}

__global__ __launch_bounds__(256) void bin_kernel(const int* __restrict__ rows,
                                                  const int* __restrict__ cols,
                                                  const float* __restrict__ vals,
                                                  int* __restrict__ cursor,
                                                  int* __restrict__ scol,
                                                  float* __restrict__ sval) {
    int e = blockIdx.x * 256 + threadIdx.x;
    if (e < N_EDGES) {
        int r = rows[e];
        int pos = atomicAdd(&cursor[r], 1);
        scol[pos] = cols[e];
        sval[pos] = vals[e];
    }
}

// ---------------------------------------------------------------------------
// SpMM: out[r] = bias + sum_{e in row r} val[e] * support[col[e]]
// One wave per row; lane handles 2 of the 128 output columns.
// ---------------------------------------------------------------------------
__global__ __launch_bounds__(256) void spmm_kernel(const int* __restrict__ row_ptr,
                                                   const int* __restrict__ scol,
                                                   const float* __restrict__ sval,
                                                   const float* __restrict__ support,
                                                   const float* __restrict__ bias,
                                                   float* __restrict__ out) {
    const int wave = threadIdx.x >> 6;
    const int lane = threadIdx.x & 63;
    const int row = blockIdx.x * 4 + wave;
    if (row >= N_NODES) return;
    const int d0 = lane * 2;

    float2 acc = *(const float2*)&bias[d0];
    int e = row_ptr[row];
    const int end = row_ptr[row + 1];

    for (; e + 2 <= end; e += 2) {
        int c0 = scol[e];
        int c1 = scol[e + 1];
        float v0 = sval[e];
        float v1 = sval[e + 1];
        float2 s0 = *(const float2*)&support[(size_t)c0 * D_OUT + d0];
        float2 s1 = *(const float2*)&support[(size_t)c1 * D_OUT + d0];
        acc.x = fmaf(v0, s0.x, acc.x);
        acc.y = fmaf(v0, s0.y, acc.y);
        acc.x = fmaf(v1, s1.x, acc.x);
        acc.y = fmaf(v1, s1.y, acc.y);
    }
    if (e < end) {
        int c = scol[e];
        float v = sval[e];
        float2 s = *(const float2*)&support[(size_t)c * D_OUT + d0];
        acc.x = fmaf(v, s.x, acc.x);
        acc.y = fmaf(v, s.y, acc.y);
    }
    *(float2*)&out[(size_t)row * D_OUT + d0] = acc;
}

// ---------------------------------------------------------------------------
extern "C" void kernel_launch(void* const* d_in, const int* in_sizes, int n_in,
                              void* d_out, int out_size, void* d_ws, size_t ws_size,
                              hipStream_t stream) {
    const float* X    = (const float*)d_in[0];   // [N, 256]
    const int*   rows = (const int*)  d_in[1];   // [E]
    const int*   cols = (const int*)  d_in[2];   // [E]
    const float* vals = (const float*)d_in[3];   // [E]
    const float* W    = (const float*)d_in[4];   // [256, 128]
    const float* bias = (const float*)d_in[5];   // [128]
    float* out = (float*)d_out;

    // workspace carve-up (16B aligned slices)
    char* p = (char*)d_ws;
    auto take = [&](size_t bytes) {
        char* r = p;
        p += (bytes + 255) & ~(size_t)255;
        return r;
    };
    float* support      = (float*)take((size_t)N_NODES * D_OUT * 4);  // 51.2 MB
    int*   counts       = (int*)  take((size_t)N_NODES * 4);
    int*   lexcl        = (int*)  take((size_t)N_NODES * 4);
    int*   row_ptr      = (int*)  take((size_t)(N_NODES + 1) * 4);
    int*   cursor       = (int*)  take((size_t)N_NODES * 4);
    int*   partials     = (int*)  take(64 * 4);
    int*   partial_base = (int*)  take(64 * 4);
    int*   scol         = (int*)  take((size_t)N_EDGES * 4);
    float* sval         = (float*)take((size_t)N_EDGES * 4);

    // GEMM (independent of CSR build)
    gemm_kernel<<<(N_NODES + 63) / 64, 256, 0, stream>>>(X, W, support);

    // CSR build
    hipMemsetAsync(counts, 0, (size_t)N_NODES * 4, stream);
    hist_kernel<<<(N_EDGES + 255) / 256, 256, 0, stream>>>(rows, counts);
    scan1_kernel<<<SCAN_NBLK, 256, 0, stream>>>(counts, lexcl, partials);
    scan2_kernel<<<1, 64, 0, stream>>>(partials, partial_base);
    scan3_kernel<<<SCAN_NBLK, 256, 0, stream>>>(lexcl, partial_base, row_ptr, cursor);
    bin_kernel<<<(N_EDGES + 255) / 256, 256, 0, stream>>>(rows, cols, vals, cursor, scol, sval);

    // SpMM + bias
    spmm_kernel<<<(N_NODES + 3) / 4, 256, 0, stream>>>(row_ptr, scol, sval, support, bias, out);
}

// Round 2
// 461.365 us; speedup vs baseline: 1.1791x; 1.1791x over previous
//
#include <hip/hip_runtime.h>
#include <hip/hip_bf16.h>

#define N_NODES 100000
#define N_EDGES 1600000
#define D_IN 256
#define D_OUT 128

typedef __attribute__((ext_vector_type(8))) short bf16x8;
typedef __attribute__((ext_vector_type(4))) float f32x4;

__device__ inline ushort f2bf(float f) {
    __hip_bfloat16 h = __float2bfloat16(f);
    union { __hip_bfloat16 h; ushort u; } cvt;
    cvt.h = h;
    return cvt.u;
}

__device__ inline float bflo(uint u) { return __uint_as_float(u << 16); }
__device__ inline float bfhi(uint u) { return __uint_as_float(u & 0xffff0000u); }

// ---------------------------------------------------------------------------
// GEMM: supp[N,128](bf16) = X[N,256](f32) @ W[256,128](f32), MFMA bf16.
// Block: 256 thr (4 waves), 128 rows/block (32 rows/wave, 2 m-tiles).
// W staged in LDS transposed Wt[n][k], bf16, 16B-chunk XOR swizzle.
// ---------------------------------------------------------------------------
__global__ __launch_bounds__(256) void gemm_kernel(const float* __restrict__ X,
                                                   const float* __restrict__ W,
                                                   ushort* __restrict__ supp) {
    __shared__ ushort Wt[128 * 256];   // 64 KB

    const int tid = threadIdx.x;
    // stage W -> LDS: element (n,k) at n*256 + ((k>>3)^(n&7))*8 + (k&7)
    for (int idx = tid; idx < 128 * 128; idx += 256) {
        int n  = idx & 127;
        int k  = (idx >> 7) * 2;
        float w0 = W[(size_t)k * D_OUT + n];
        float w1 = W[(size_t)(k + 1) * D_OUT + n];
        uint b = ((uint)f2bf(w1) << 16) | f2bf(w0);
        int slot = ((k >> 3) ^ (n & 7));
        uint off = (uint)n * 256 + (uint)slot * 8 + (k & 7);
        *(uint*)&Wt[off] = b;
    }
    __syncthreads();

    const int w = tid >> 6;
    const int l = tid & 63;
    const int c = l & 15;       // M row (A) / N col (B) within 16-tile
    const int g = l >> 4;       // k-group
    const int rbase = blockIdx.x * 128 + w * 32;

    int r0 = rbase + c;       if (r0 > N_NODES - 1) r0 = N_NODES - 1;
    int r1 = rbase + 16 + c;  if (r1 > N_NODES - 1) r1 = N_NODES - 1;
    const float* x0 = X + (size_t)r0 * D_IN + g * 8;
    const float* x1 = X + (size_t)r1 * D_IN + g * 8;

    f32x4 acc[2][8];
    #pragma unroll
    for (int mi = 0; mi < 2; ++mi)
        #pragma unroll
        for (int j = 0; j < 8; ++j)
            acc[mi][j] = (f32x4){0.f, 0.f, 0.f, 0.f};

    #pragma unroll
    for (int s = 0; s < 8; ++s) {       // K-step = 32
        float4 a0l = *(const float4*)(x0 + s * 32);
        float4 a0h = *(const float4*)(x0 + s * 32 + 4);
        float4 a1l = *(const float4*)(x1 + s * 32);
        float4 a1h = *(const float4*)(x1 + s * 32 + 4);
        bf16x8 a0, a1;
        a0[0] = (short)f2bf(a0l.x); a0[1] = (short)f2bf(a0l.y);
        a0[2] = (short)f2bf(a0l.z); a0[3] = (short)f2bf(a0l.w);
        a0[4] = (short)f2bf(a0h.x); a0[5] = (short)f2bf(a0h.y);
        a0[6] = (short)f2bf(a0h.z); a0[7] = (short)f2bf(a0h.w);
        a1[0] = (short)f2bf(a1l.x); a1[1] = (short)f2bf(a1l.y);
        a1[2] = (short)f2bf(a1l.z); a1[3] = (short)f2bf(a1l.w);
        a1[4] = (short)f2bf(a1h.x); a1[5] = (short)f2bf(a1h.y);
        a1[6] = (short)f2bf(a1h.z); a1[7] = (short)f2bf(a1h.w);

        #pragma unroll
        for (int j = 0; j < 8; ++j) {
            // B frag: col = 16j+c, k = 32s + 8g + i  (chunk kc = 4s+g)
            const bf16x8 b = *(const bf16x8*)
                &Wt[(uint)(16 * j + c) * 256 + (uint)(((4 * s + g) ^ (c & 7)) * 8)];
            acc[0][j] = __builtin_amdgcn_mfma_f32_16x16x32_bf16(a0, b, acc[0][j], 0, 0, 0);
            acc[1][j] = __builtin_amdgcn_mfma_f32_16x16x32_bf16(a1, b, acc[1][j], 0, 0, 0);
        }
    }

    // D layout: col = lane&15, row = 4*(lane>>4) + reg
    #pragma unroll
    for (int mi = 0; mi < 2; ++mi) {
        int rb = rbase + mi * 16 + g * 4;
        #pragma unroll
        for (int reg = 0; reg < 4; ++reg) {
            int r = rb + reg;
            if (r < N_NODES) {
                #pragma unroll
                for (int j = 0; j < 8; ++j)
                    supp[(size_t)r * D_OUT + 16 * j + c] = f2bf(acc[mi][j][reg]);
            }
        }
    }
}

// ---------------------------------------------------------------------------
// CSR build: histogram -> exclusive scan -> bin (interleaved {col,val})
// ---------------------------------------------------------------------------
__global__ __launch_bounds__(256) void hist_kernel(const int4* __restrict__ rows4,
                                                   int* __restrict__ counts) {
    int idx = blockIdx.x * 256 + threadIdx.x;
    if (idx < N_EDGES / 4) {
        int4 r = rows4[idx];
        atomicAdd(&counts[r.x], 1);
        atomicAdd(&counts[r.y], 1);
        atomicAdd(&counts[r.z], 1);
        atomicAdd(&counts[r.w], 1);
    }
}

#define SCAN_CHUNK 2048
#define SCAN_NBLK ((N_NODES + SCAN_CHUNK - 1) / SCAN_CHUNK)   // 49

__global__ __launch_bounds__(256) void scan1_kernel(const int* __restrict__ counts,
                                                    int* __restrict__ lexcl,
                                                    int* __restrict__ partials) {
    __shared__ int tsum[256];
    const int tid = threadIdx.x;
    const int base = blockIdx.x * SCAN_CHUNK + tid * 8;
    int vals[8];
    int s = 0;
    #pragma unroll
    for (int j = 0; j < 8; ++j) {
        int i = base + j;
        int v = (i < N_NODES) ? counts[i] : 0;
        vals[j] = s;
        s += v;
    }
    tsum[tid] = s;
    __syncthreads();
    for (int off = 1; off < 256; off <<= 1) {
        int t = (tid >= off) ? tsum[tid - off] : 0;
        __syncthreads();
        tsum[tid] += t;
        __syncthreads();
    }
    int incl = tsum[tid];
    int texcl = incl - s;
    if (tid == 255) partials[blockIdx.x] = incl;
    #pragma unroll
    for (int j = 0; j < 8; ++j) {
        int i = base + j;
        if (i < N_NODES) lexcl[i] = texcl + vals[j];
    }
}

__global__ __launch_bounds__(64) void scan2_kernel(const int* __restrict__ partials,
                                                   int* __restrict__ partial_base) {
    int tid = threadIdx.x;
    int v = (tid < SCAN_NBLK) ? partials[tid] : 0;
    int x = v;
    #pragma unroll
    for (int off = 1; off < 64; off <<= 1) {
        int t = __shfl_up(x, off, 64);
        if (tid >= off) x += t;
    }
    if (tid < SCAN_NBLK) partial_base[tid] = x - v;
}

__global__ __launch_bounds__(256) void scan3_kernel(const int* __restrict__ lexcl,
                                                    const int* __restrict__ partial_base,
                                                    int* __restrict__ row_ptr,
                                                    int* __restrict__ cursor) {
    const int pb = partial_base[blockIdx.x];
    const int base = blockIdx.x * SCAN_CHUNK + threadIdx.x * 8;
    #pragma unroll
    for (int j = 0; j < 8; ++j) {
        int i = base + j;
        if (i < N_NODES) {
            int v = pb + lexcl[i];
            row_ptr[i] = v;
            cursor[i]  = v;
        }
    }
    if (blockIdx.x == 0 && threadIdx.x == 0) row_ptr[N_NODES] = N_EDGES;
}

__global__ __launch_bounds__(256) void bin_kernel(const int4* __restrict__ rows4,
                                                  const int4* __restrict__ cols4,
                                                  const float4* __restrict__ vals4,
                                                  int* __restrict__ cursor,
                                                  float2* __restrict__ edata) {
    int idx = blockIdx.x * 256 + threadIdx.x;
    if (idx < N_EDGES / 4) {
        int4 r = rows4[idx];
        int4 cc = cols4[idx];
        float4 v = vals4[idx];
        int p0 = atomicAdd(&cursor[r.x], 1);
        edata[p0] = make_float2(__int_as_float(cc.x), v.x);
        int p1 = atomicAdd(&cursor[r.y], 1);
        edata[p1] = make_float2(__int_as_float(cc.y), v.y);
        int p2 = atomicAdd(&cursor[r.z], 1);
        edata[p2] = make_float2(__int_as_float(cc.z), v.z);
        int p3 = atomicAdd(&cursor[r.w], 1);
        edata[p3] = make_float2(__int_as_float(cc.w), v.w);
    }
}

// ---------------------------------------------------------------------------
// SpMM: out[r] = bias + sum edges v * supp_bf16[col]; wave per row, unroll 4.
// ---------------------------------------------------------------------------
__global__ __launch_bounds__(256) void spmm_kernel(const int* __restrict__ row_ptr,
                                                   const float2* __restrict__ edata,
                                                   const ushort* __restrict__ supp,
                                                   const float* __restrict__ bias,
                                                   float* __restrict__ out) {
    const int wave = threadIdx.x >> 6;
    const int lane = threadIdx.x & 63;
    const int row = blockIdx.x * 4 + wave;
    if (row >= N_NODES) return;
    const int d0 = lane * 2;

    float2 acc = *(const float2*)&bias[d0];
    int e = row_ptr[row];
    const int end = row_ptr[row + 1];

    for (; e + 4 <= end; e += 4) {
        float2 e0 = edata[e];
        float2 e1 = edata[e + 1];
        float2 e2 = edata[e + 2];
        float2 e3 = edata[e + 3];
        uint s0 = *(const uint*)(supp + (size_t)__float_as_int(e0.x) * D_OUT + d0);
        uint s1 = *(const uint*)(supp + (size_t)__float_as_int(e1.x) * D_OUT + d0);
        uint s2 = *(const uint*)(supp + (size_t)__float_as_int(e2.x) * D_OUT + d0);
        uint s3 = *(const uint*)(supp + (size_t)__float_as_int(e3.x) * D_OUT + d0);
        acc.x = fmaf(e0.y, bflo(s0), acc.x);
        acc.y = fmaf(e0.y, bfhi(s0), acc.y);
        acc.x = fmaf(e1.y, bflo(s1), acc.x);
        acc.y = fmaf(e1.y, bfhi(s1), acc.y);
        acc.x = fmaf(e2.y, bflo(s2), acc.x);
        acc.y = fmaf(e2.y, bfhi(s2), acc.y);
        acc.x = fmaf(e3.y, bflo(s3), acc.x);
        acc.y = fmaf(e3.y, bfhi(s3), acc.y);
    }
    for (; e < end; ++e) {
        float2 ed = edata[e];
        uint s = *(const uint*)(supp + (size_t)__float_as_int(ed.x) * D_OUT + d0);
        acc.x = fmaf(ed.y, bflo(s), acc.x);
        acc.y = fmaf(ed.y, bfhi(s), acc.y);
    }
    *(float2*)&out[(size_t)row * D_OUT + d0] = acc;
}

// ---------------------------------------------------------------------------
extern "C" void kernel_launch(void* const* d_in, const int* in_sizes, int n_in,
                              void* d_out, int out_size, void* d_ws, size_t ws_size,
                              hipStream_t stream) {
    const float* X    = (const float*)d_in[0];
    const int*   rows = (const int*)  d_in[1];
    const int*   cols = (const int*)  d_in[2];
    const float* vals = (const float*)d_in[3];
    const float* W    = (const float*)d_in[4];
    const float* bias = (const float*)d_in[5];
    float* out = (float*)d_out;

    char* p = (char*)d_ws;
    auto take = [&](size_t bytes) {
        char* r = p;
        p += (bytes + 255) & ~(size_t)255;
        return r;
    };
    ushort* supp        = (ushort*)take((size_t)N_NODES * D_OUT * 2);  // 25.6 MB
    int*    counts      = (int*)   take((size_t)N_NODES * 4);
    int*    lexcl       = (int*)   take((size_t)N_NODES * 4);
    int*    row_ptr     = (int*)   take((size_t)(N_NODES + 1) * 4);
    int*    cursor      = (int*)   take((size_t)N_NODES * 4);
    int*    partials    = (int*)   take(64 * 4);
    int*    partial_base= (int*)   take(64 * 4);
    float2* edata       = (float2*)take((size_t)N_EDGES * 8);          // 12.8 MB

    // GEMM (bf16 MFMA)
    gemm_kernel<<<(N_NODES + 127) / 128, 256, 0, stream>>>(X, W, supp);

    // CSR build
    hipMemsetAsync(counts, 0, (size_t)N_NODES * 4, stream);
    hist_kernel<<<(N_EDGES / 4 + 255) / 256, 256, 0, stream>>>((const int4*)rows, counts);
    scan1_kernel<<<SCAN_NBLK, 256, 0, stream>>>(counts, lexcl, partials);
    scan2_kernel<<<1, 64, 0, stream>>>(partials, partial_base);
    scan3_kernel<<<SCAN_NBLK, 256, 0, stream>>>(lexcl, partial_base, row_ptr, cursor);
    bin_kernel<<<(N_EDGES / 4 + 255) / 256, 256, 0, stream>>>(
        (const int4*)rows, (const int4*)cols, (const float4*)vals, cursor, edata);

    // SpMM + bias
    spmm_kernel<<<(N_NODES + 3) / 4, 256, 0, stream>>>(row_ptr, edata, supp, bias, out);
}

// Round 3
// 336.826 us; speedup vs baseline: 1.6151x; 1.3697x over previous
//
#include <hip/hip_runtime.h>
#include <hip/hip_bf16.h>

#define N_NODES 100000
#define N_EDGES 1600000
#define D_IN 256
#define D_OUT 128
#define NB 1563          // ceil(N_NODES / 64) buckets of 64 rows
#define CHUNK 8192       // edges per partition block
#define NCHUNK ((N_EDGES + CHUNK - 1) / CHUNK)   // 196
#define P2_CAP 4096      // max edges per bucket (mean 1024; 96 sigma margin)

typedef __attribute__((ext_vector_type(8))) short bf16x8;
typedef __attribute__((ext_vector_type(4))) float f32x4;

__device__ inline ushort f2bf(float f) {
    __hip_bfloat16 h = __float2bfloat16(f);
    union { __hip_bfloat16 h; ushort u; } cvt;
    cvt.h = h;
    return cvt.u;
}

__device__ inline float bflo(uint u) { return __uint_as_float(u << 16); }
__device__ inline float bfhi(uint u) { return __uint_as_float(u & 0xffff0000u); }

// ---------------------------------------------------------------------------
// GEMM: supp[N,128](bf16) = X[N,256](f32) @ W[256,128](f32), MFMA bf16.
// ---------------------------------------------------------------------------
__global__ __launch_bounds__(256) void gemm_kernel(const float* __restrict__ X,
                                                   const float* __restrict__ W,
                                                   ushort* __restrict__ supp) {
    __shared__ ushort Wt[128 * 256];   // 64 KB

    const int tid = threadIdx.x;
    for (int idx = tid; idx < 128 * 128; idx += 256) {
        int n  = idx & 127;
        int k  = (idx >> 7) * 2;
        float w0 = W[(size_t)k * D_OUT + n];
        float w1 = W[(size_t)(k + 1) * D_OUT + n];
        uint b = ((uint)f2bf(w1) << 16) | f2bf(w0);
        int slot = ((k >> 3) ^ (n & 7));
        uint off = (uint)n * 256 + (uint)slot * 8 + (k & 7);
        *(uint*)&Wt[off] = b;
    }
    __syncthreads();

    const int w = tid >> 6;
    const int l = tid & 63;
    const int c = l & 15;
    const int g = l >> 4;
    const int rbase = blockIdx.x * 128 + w * 32;

    int r0 = rbase + c;       if (r0 > N_NODES - 1) r0 = N_NODES - 1;
    int r1 = rbase + 16 + c;  if (r1 > N_NODES - 1) r1 = N_NODES - 1;
    const float* x0 = X + (size_t)r0 * D_IN + g * 8;
    const float* x1 = X + (size_t)r1 * D_IN + g * 8;

    f32x4 acc[2][8];
    #pragma unroll
    for (int mi = 0; mi < 2; ++mi)
        #pragma unroll
        for (int j = 0; j < 8; ++j)
            acc[mi][j] = (f32x4){0.f, 0.f, 0.f, 0.f};

    #pragma unroll
    for (int s = 0; s < 8; ++s) {
        float4 a0l = *(const float4*)(x0 + s * 32);
        float4 a0h = *(const float4*)(x0 + s * 32 + 4);
        float4 a1l = *(const float4*)(x1 + s * 32);
        float4 a1h = *(const float4*)(x1 + s * 32 + 4);
        bf16x8 a0, a1;
        a0[0] = (short)f2bf(a0l.x); a0[1] = (short)f2bf(a0l.y);
        a0[2] = (short)f2bf(a0l.z); a0[3] = (short)f2bf(a0l.w);
        a0[4] = (short)f2bf(a0h.x); a0[5] = (short)f2bf(a0h.y);
        a0[6] = (short)f2bf(a0h.z); a0[7] = (short)f2bf(a0h.w);
        a1[0] = (short)f2bf(a1l.x); a1[1] = (short)f2bf(a1l.y);
        a1[2] = (short)f2bf(a1l.z); a1[3] = (short)f2bf(a1l.w);
        a1[4] = (short)f2bf(a1h.x); a1[5] = (short)f2bf(a1h.y);
        a1[6] = (short)f2bf(a1h.z); a1[7] = (short)f2bf(a1h.w);

        #pragma unroll
        for (int j = 0; j < 8; ++j) {
            const bf16x8 b = *(const bf16x8*)
                &Wt[(uint)(16 * j + c) * 256 + (uint)(((4 * s + g) ^ (c & 7)) * 8)];
            acc[0][j] = __builtin_amdgcn_mfma_f32_16x16x32_bf16(a0, b, acc[0][j], 0, 0, 0);
            acc[1][j] = __builtin_amdgcn_mfma_f32_16x16x32_bf16(a1, b, acc[1][j], 0, 0, 0);
        }
    }

    #pragma unroll
    for (int mi = 0; mi < 2; ++mi) {
        int rb = rbase + mi * 16 + g * 4;
        #pragma unroll
        for (int reg = 0; reg < 4; ++reg) {
            int r = rb + reg;
            if (r < N_NODES) {
                #pragma unroll
                for (int j = 0; j < 8; ++j)
                    supp[(size_t)r * D_OUT + 16 * j + c] = f2bf(acc[mi][j][reg]);
            }
        }
    }
}

// ---------------------------------------------------------------------------
// bhist: per-block LDS histogram over NB buckets, flush with global atomics
// ---------------------------------------------------------------------------
__global__ __launch_bounds__(256) void bhist_kernel(const int4* __restrict__ rows4,
                                                    int* __restrict__ bcnt) {
    __shared__ int cnt[NB];
    const int tid = threadIdx.x;
    for (int i = tid; i < NB; i += 256) cnt[i] = 0;
    __syncthreads();
    const int i4base = blockIdx.x * (CHUNK / 4);
    #pragma unroll
    for (int j = 0; j < 8; ++j) {
        int i4 = i4base + j * 256 + tid;
        if (i4 < N_EDGES / 4) {
            int4 r = rows4[i4];
            atomicAdd(&cnt[r.x >> 6], 1);
            atomicAdd(&cnt[r.y >> 6], 1);
            atomicAdd(&cnt[r.z >> 6], 1);
            atomicAdd(&cnt[r.w >> 6], 1);
        }
    }
    __syncthreads();
    for (int i = tid; i < NB; i += 256) {
        int c = cnt[i];
        if (c) atomicAdd(&bcnt[i], c);
    }
}

// ---------------------------------------------------------------------------
// bscan: single-block exclusive scan of NB bucket counts
// ---------------------------------------------------------------------------
__global__ __launch_bounds__(256) void bscan_kernel(const int* __restrict__ bcnt,
                                                    int* __restrict__ bucket_base,
                                                    int* __restrict__ gcursor,
                                                    int* __restrict__ row_ptr) {
    __shared__ int tsum[256];
    const int tid = threadIdx.x;
    int loc[7];
    int s = 0;
    #pragma unroll
    for (int j = 0; j < 7; ++j) {
        int i = tid * 7 + j;
        int v = (i < NB) ? bcnt[i] : 0;
        loc[j] = s;
        s += v;
    }
    tsum[tid] = s;
    __syncthreads();
    for (int off = 1; off < 256; off <<= 1) {
        int t = (tid >= off) ? tsum[tid - off] : 0;
        __syncthreads();
        tsum[tid] += t;
        __syncthreads();
    }
    int excl = tsum[tid] - s;
    #pragma unroll
    for (int j = 0; j < 7; ++j) {
        int i = tid * 7 + j;
        if (i < NB) {
            int v = excl + loc[j];
            bucket_base[i] = v;
            gcursor[i] = v;
        }
    }
    if (tid == 255) {
        bucket_base[NB] = N_EDGES;
        row_ptr[N_NODES] = N_EDGES;
    }
}

// ---------------------------------------------------------------------------
// part: per-block reserve + scatter. Records: (row_local<<17 | col, val)
// ---------------------------------------------------------------------------
__global__ __launch_bounds__(256) void part_kernel(const int4* __restrict__ rows4,
                                                   const int4* __restrict__ cols4,
                                                   const float4* __restrict__ vals4,
                                                   int* __restrict__ gcursor,
                                                   float2* __restrict__ edata) {
    __shared__ int cnt[NB];
    __shared__ int lbase[NB];
    const int tid = threadIdx.x;
    for (int i = tid; i < NB; i += 256) cnt[i] = 0;
    __syncthreads();

    const int i4base = blockIdx.x * (CHUNK / 4);
    // phase A: local histogram
    #pragma unroll
    for (int j = 0; j < 8; ++j) {
        int i4 = i4base + j * 256 + tid;
        if (i4 < N_EDGES / 4) {
            int4 r = rows4[i4];
            atomicAdd(&cnt[r.x >> 6], 1);
            atomicAdd(&cnt[r.y >> 6], 1);
            atomicAdd(&cnt[r.z >> 6], 1);
            atomicAdd(&cnt[r.w >> 6], 1);
        }
    }
    __syncthreads();
    // phase B: reserve contiguous ranges
    for (int i = tid; i < NB; i += 256) {
        int c = cnt[i];
        lbase[i] = c ? atomicAdd(&gcursor[i], c) : 0;
        cnt[i] = 0;
    }
    __syncthreads();
    // phase C: scatter
    #pragma unroll
    for (int j = 0; j < 8; ++j) {
        int i4 = i4base + j * 256 + tid;
        if (i4 < N_EDGES / 4) {
            int4 r = rows4[i4];
            int4 cc = cols4[i4];
            float4 v = vals4[i4];
            int b, rk;
            b = r.x >> 6; rk = atomicAdd(&cnt[b], 1);
            edata[lbase[b] + rk] = make_float2(__int_as_float(((r.x & 63) << 17) | cc.x), v.x);
            b = r.y >> 6; rk = atomicAdd(&cnt[b], 1);
            edata[lbase[b] + rk] = make_float2(__int_as_float(((r.y & 63) << 17) | cc.y), v.y);
            b = r.z >> 6; rk = atomicAdd(&cnt[b], 1);
            edata[lbase[b] + rk] = make_float2(__int_as_float(((r.z & 63) << 17) | cc.z), v.z);
            b = r.w >> 6; rk = atomicAdd(&cnt[b], 1);
            edata[lbase[b] + rk] = make_float2(__int_as_float(((r.w & 63) << 17) | cc.w), v.w);
        }
    }
}

// ---------------------------------------------------------------------------
// sortb: one block per bucket; LDS counting sort by row_local -> exact CSR
// ---------------------------------------------------------------------------
__global__ __launch_bounds__(256) void sortb_kernel(const int* __restrict__ bucket_base,
                                                    const float2* __restrict__ edata,
                                                    float2* __restrict__ edata2,
                                                    int* __restrict__ row_ptr) {
    __shared__ int cnt[64];
    __shared__ int cur[64];
    __shared__ float2 sorted[P2_CAP];
    const int b = blockIdx.x;
    const int tid = threadIdx.x;
    const int base = bucket_base[b];
    const int n = bucket_base[b + 1] - base;

    if (tid < 64) cnt[tid] = 0;
    __syncthreads();

    uint pk[16];
    float vv[16];
    #pragma unroll
    for (int j = 0; j < 16; ++j) {
        int idx = tid + 256 * j;
        if (idx < n) {
            float2 rec = edata[base + idx];
            pk[j] = (uint)__float_as_int(rec.x);
            vv[j] = rec.y;
            atomicAdd(&cnt[pk[j] >> 17], 1);
        }
    }
    __syncthreads();

    if (tid < 64) {
        int c = cnt[tid];
        int x = c;
        #pragma unroll
        for (int off = 1; off < 64; off <<= 1) {
            int t = __shfl_up(x, off, 64);
            if (tid >= off) x += t;
        }
        int excl = x - c;
        cur[tid] = excl;
        int row = b * 64 + tid;
        if (row < N_NODES) row_ptr[row] = base + excl;
    }
    __syncthreads();

    #pragma unroll
    for (int j = 0; j < 16; ++j) {
        int idx = tid + 256 * j;
        if (idx < n) {
            int r = pk[j] >> 17;
            int rk = atomicAdd(&cur[r], 1);
            sorted[rk] = make_float2(__int_as_float((int)(pk[j] & 0x1FFFF)), vv[j]);
        }
    }
    __syncthreads();

    for (int i = tid; i < n; i += 256)
        edata2[base + i] = sorted[i];
}

// ---------------------------------------------------------------------------
// SpMM: out[r] = bias + sum edges v * supp_bf16[col]; wave per row, unroll 4.
// ---------------------------------------------------------------------------
__global__ __launch_bounds__(256) void spmm_kernel(const int* __restrict__ row_ptr,
                                                   const float2* __restrict__ edata,
                                                   const ushort* __restrict__ supp,
                                                   const float* __restrict__ bias,
                                                   float* __restrict__ out) {
    const int wave = threadIdx.x >> 6;
    const int lane = threadIdx.x & 63;
    const int row = blockIdx.x * 4 + wave;
    if (row >= N_NODES) return;
    const int d0 = lane * 2;

    float2 acc = *(const float2*)&bias[d0];
    int e = row_ptr[row];
    const int end = row_ptr[row + 1];

    for (; e + 4 <= end; e += 4) {
        float2 e0 = edata[e];
        float2 e1 = edata[e + 1];
        float2 e2 = edata[e + 2];
        float2 e3 = edata[e + 3];
        uint s0 = *(const uint*)(supp + (size_t)__float_as_int(e0.x) * D_OUT + d0);
        uint s1 = *(const uint*)(supp + (size_t)__float_as_int(e1.x) * D_OUT + d0);
        uint s2 = *(const uint*)(supp + (size_t)__float_as_int(e2.x) * D_OUT + d0);
        uint s3 = *(const uint*)(supp + (size_t)__float_as_int(e3.x) * D_OUT + d0);
        acc.x = fmaf(e0.y, bflo(s0), acc.x);
        acc.y = fmaf(e0.y, bfhi(s0), acc.y);
        acc.x = fmaf(e1.y, bflo(s1), acc.x);
        acc.y = fmaf(e1.y, bfhi(s1), acc.y);
        acc.x = fmaf(e2.y, bflo(s2), acc.x);
        acc.y = fmaf(e2.y, bfhi(s2), acc.y);
        acc.x = fmaf(e3.y, bflo(s3), acc.x);
        acc.y = fmaf(e3.y, bfhi(s3), acc.y);
    }
    for (; e < end; ++e) {
        float2 ed = edata[e];
        uint s = *(const uint*)(supp + (size_t)__float_as_int(ed.x) * D_OUT + d0);
        acc.x = fmaf(ed.y, bflo(s), acc.x);
        acc.y = fmaf(ed.y, bfhi(s), acc.y);
    }
    *(float2*)&out[(size_t)row * D_OUT + d0] = acc;
}

// ---------------------------------------------------------------------------
extern "C" void kernel_launch(void* const* d_in, const int* in_sizes, int n_in,
                              void* d_out, int out_size, void* d_ws, size_t ws_size,
                              hipStream_t stream) {
    const float* X    = (const float*)d_in[0];
    const int*   rows = (const int*)  d_in[1];
    const int*   cols = (const int*)  d_in[2];
    const float* vals = (const float*)d_in[3];
    const float* W    = (const float*)d_in[4];
    const float* bias = (const float*)d_in[5];
    float* out = (float*)d_out;

    char* p = (char*)d_ws;
    auto take = [&](size_t bytes) {
        char* r = p;
        p += (bytes + 255) & ~(size_t)255;
        return r;
    };
    ushort* supp        = (ushort*)take((size_t)N_NODES * D_OUT * 2);   // 25.6 MB
    float2* edata       = (float2*)take((size_t)N_EDGES * 8);           // 12.8 MB
    float2* edata2      = (float2*)take((size_t)N_EDGES * 8);           // 12.8 MB
    int*    row_ptr     = (int*)   take((size_t)(N_NODES + 1) * 4);
    int*    bcnt        = (int*)   take((size_t)(NB + 1) * 4);
    int*    bucket_base = (int*)   take((size_t)(NB + 1) * 4);
    int*    gcursor     = (int*)   take((size_t)(NB + 1) * 4);

    // GEMM (bf16 MFMA) — independent of edge pipeline
    gemm_kernel<<<(N_NODES + 127) / 128, 256, 0, stream>>>(X, W, supp);

    // bucket partition + exact CSR
    hipMemsetAsync(bcnt, 0, (size_t)NB * 4, stream);
    bhist_kernel<<<NCHUNK, 256, 0, stream>>>((const int4*)rows, bcnt);
    bscan_kernel<<<1, 256, 0, stream>>>(bcnt, bucket_base, gcursor, row_ptr);
    part_kernel<<<NCHUNK, 256, 0, stream>>>((const int4*)rows, (const int4*)cols,
                                            (const float4*)vals, gcursor, edata);
    sortb_kernel<<<NB, 256, 0, stream>>>(bucket_base, edata, edata2, row_ptr);

    // SpMM + bias
    spmm_kernel<<<(N_NODES + 3) / 4, 256, 0, stream>>>(row_ptr, edata2, supp, bias, out);
}